// Round 4
// baseline (206.548 us; speedup 1.0000x reference)
//
#include <hip/hip_runtime.h>
#include <math.h>

// Shapes: B=8, N=256, NID=64, V=GH=128, PHI=256, RHO=128
#define NB 8

// ---------------------------------------------------------------------------
// Common layout (128-f kernels): 512 threads, q=t&31 (f-quad), u=t>>5 (16
// K-slices), wave w=t>>6. u-pairs (2w,2w+1) share a wave -> shfl_down(32)
// pre-reduces partials so LDS part is [8w][8r][128f] = 32 KB.
// Grid 256 = 1 block/CU, 8 rows/block: halves replicated L2 weight traffic
// vs 4-row/512-block variants.
// ---------------------------------------------------------------------------

// k_embed: H = relu(X@w1+b1)@w2+b2. 8 rows/block, grid 256.
__global__ __launch_bounds__(512, 2) void k_embed(const float* __restrict__ X,
        const float* __restrict__ w1, const float* __restrict__ b1,
        const float* __restrict__ w2, const float* __restrict__ b2,
        float* __restrict__ H, float* __restrict__ pools) {
    const int r0 = blockIdx.x * 8;
    const int t = threadIdx.x, q = t & 31, u = t >> 5, w = t >> 6;
    __shared__ __align__(16) float part[8192];   // [8w][8r][128f]
    __shared__ __align__(16) float xq[512];      // [k][r]
    __shared__ __align__(16) float h1q[1024];    // [k][r]
    if (blockIdx.x < 8) pools[blockIdx.x * 512 + t] = 0.f;
    {   // xq[k*8+r] = X[(r0+r)*64+k]
        int r = t >> 6, k = t & 63;
        xq[k * 8 + r] = X[(size_t)(r0 + r) * 64 + k];
    }
    __syncthreads();
    {   // L1: K=64, thread covers k in [u*4, u*4+4)
        float acc[32];
        #pragma unroll
        for (int i = 0; i < 32; ++i) acc[i] = 0.f;
        #pragma unroll
        for (int kk = 0; kk < 4; ++kk) {
            int k = u * 4 + kk;
            float4 w4 = *(const float4*)&w1[(size_t)k * 128 + q * 4];
            float wc[4] = {w4.x, w4.y, w4.z, w4.w};
            float4 xa = *(const float4*)&xq[k * 8];
            float4 xb = *(const float4*)&xq[k * 8 + 4];
            float xr[8] = {xa.x, xa.y, xa.z, xa.w, xb.x, xb.y, xb.z, xb.w};
            #pragma unroll
            for (int r = 0; r < 8; ++r)
                #pragma unroll
                for (int c = 0; c < 4; ++c)
                    acc[r * 4 + c] = fmaf(xr[r], wc[c], acc[r * 4 + c]);
        }
        #pragma unroll
        for (int i = 0; i < 32; ++i) acc[i] += __shfl_down(acc[i], 32, 64);
        if ((t & 63) < 32)
            #pragma unroll
            for (int r = 0; r < 8; ++r)
                *(float4*)&part[w * 1024 + r * 128 + q * 4] =
                    make_float4(acc[r*4+0], acc[r*4+1], acc[r*4+2], acc[r*4+3]);
    }
    __syncthreads();
    #pragma unroll
    for (int e = 0; e < 2; ++e) {   // combine -> h1q (relu)
        int idx = e * 512 + t;
        int r = idx >> 7, f = idx & 127;
        float s = b1[f];
        #pragma unroll
        for (int uu = 0; uu < 8; ++uu) s += part[uu * 1024 + r * 128 + f];
        h1q[f * 8 + r] = fmaxf(s, 0.f);
    }
    __syncthreads();
    {   // L2: K=128, thread covers k in [u*8, u*8+8)
        float acc[32];
        #pragma unroll
        for (int i = 0; i < 32; ++i) acc[i] = 0.f;
        #pragma unroll
        for (int kk = 0; kk < 8; ++kk) {
            int k = u * 8 + kk;
            float4 w4 = *(const float4*)&w2[(size_t)k * 128 + q * 4];
            float wc[4] = {w4.x, w4.y, w4.z, w4.w};
            float4 xa = *(const float4*)&h1q[k * 8];
            float4 xb = *(const float4*)&h1q[k * 8 + 4];
            float xr[8] = {xa.x, xa.y, xa.z, xa.w, xb.x, xb.y, xb.z, xb.w};
            #pragma unroll
            for (int r = 0; r < 8; ++r)
                #pragma unroll
                for (int c = 0; c < 4; ++c)
                    acc[r * 4 + c] = fmaf(xr[r], wc[c], acc[r * 4 + c]);
        }
        #pragma unroll
        for (int i = 0; i < 32; ++i) acc[i] += __shfl_down(acc[i], 32, 64);
        if ((t & 63) < 32)
            #pragma unroll
            for (int r = 0; r < 8; ++r)
                *(float4*)&part[w * 1024 + r * 128 + q * 4] =
                    make_float4(acc[r*4+0], acc[r*4+1], acc[r*4+2], acc[r*4+3]);
    }
    __syncthreads();
    #pragma unroll
    for (int e = 0; e < 2; ++e) {
        int idx = e * 512 + t;
        int r = idx >> 7, f = idx & 127;
        float s = b2[f];
        #pragma unroll
        for (int uu = 0; uu < 8; ++uu) s += part[uu * 1024 + r * 128 + f];
        H[(size_t)(r0 + r) * 128 + f] = s;
    }
}

// ---------------------------------------------------------------------------
// k_gcn1: relation-mean aggregation + RGCN 3-matrix linear. Block = (b, 8 j).
// Two i-sweeps (rel0, rel1) keep acc at 32 regs; H/weights direct from L2.
// ---------------------------------------------------------------------------
__global__ __launch_bounds__(512, 2) void k_gcn1(
        const float* __restrict__ A, const float* __restrict__ H,
        const float* __restrict__ Wrel, const float* __restrict__ Wroot,
        const float* __restrict__ bias, float* __restrict__ H2) {
    const int b  = blockIdx.x >> 5;
    const int j0 = (blockIdx.x & 31) * 8;
    const int t = threadIdx.x, q = t & 31, u = t >> 5, w = t >> 6;
    __shared__ __align__(16) float maskM[4096];  // [256 i][16] (8 m0 | 8 m1)
    __shared__ __align__(16) float part[8192];   // [8w][8r][128f]
    __shared__ __align__(16) float pb[3072];     // [128 k][24] root8|m0_8|m1_8
    __shared__ float cntp[512];
    __shared__ float cnt[16];
    const float* Ab = A + (size_t)b * 65536;
    const float* Hb = H + (size_t)b * 32768;
    const float* W0 = Wrel;
    const float* W1 = Wrel + 16384;

    if (t < 256) {   // masks: thread t owns row i=t, 8 columns
        float4 a0 = *(const float4*)(Ab + (size_t)t * 256 + j0);
        float4 a1 = *(const float4*)(Ab + (size_t)t * 256 + j0 + 4);
        float av[8] = {a0.x, a0.y, a0.z, a0.w, a1.x, a1.y, a1.z, a1.w};
        #pragma unroll
        for (int j = 0; j < 8; ++j) {
            maskM[t * 16 + j]     = (av[j] < 0.f) ? 1.f : 0.f;
            maskM[t * 16 + 8 + j] = (av[j] > 0.f) ? 1.f : 0.f;
        }
    }
    __syncthreads();
    {   // count partials: 32 chunks x 16 slots
        int chunk = t >> 4, slot = t & 15;
        float c = 0.f;
        #pragma unroll
        for (int qq = 0; qq < 8; ++qq) c += maskM[(chunk * 8 + qq) * 16 + slot];
        cntp[slot * 32 + chunk] = c;
    }
    __syncthreads();
    if (t < 16) {
        float s = 0.f;
        #pragma unroll
        for (int c = 0; c < 32; ++c) s += cntp[t * 32 + c];
        cnt[t] = s;
    }
    // ---- sweep rel0: i in [u*16, u*16+16) ----
    {
        float acc[32];
        #pragma unroll
        for (int i = 0; i < 32; ++i) acc[i] = 0.f;
        #pragma unroll 8
        for (int ii = 0; ii < 16; ++ii) {
            int i = u * 16 + ii;
            float4 h4 = *(const float4*)&Hb[(size_t)i * 128 + q * 4];
            float hc[4] = {h4.x, h4.y, h4.z, h4.w};
            float4 ma = *(const float4*)&maskM[i * 16];
            float4 mb = *(const float4*)&maskM[i * 16 + 4];
            float mr[8] = {ma.x, ma.y, ma.z, ma.w, mb.x, mb.y, mb.z, mb.w};
            #pragma unroll
            for (int r = 0; r < 8; ++r)
                #pragma unroll
                for (int c = 0; c < 4; ++c)
                    acc[r * 4 + c] = fmaf(mr[r], hc[c], acc[r * 4 + c]);
        }
        #pragma unroll
        for (int i = 0; i < 32; ++i) acc[i] += __shfl_down(acc[i], 32, 64);
        if ((t & 63) < 32)
            #pragma unroll
            for (int r = 0; r < 8; ++r)
                *(float4*)&part[w * 1024 + r * 128 + q * 4] =
                    make_float4(acc[r*4+0], acc[r*4+1], acc[r*4+2], acc[r*4+3]);
    }
    __syncthreads();
    #pragma unroll
    for (int e = 0; e < 2; ++e) {   // combine -> pb mean0
        int idx = e * 512 + t;
        int r = idx >> 7, f = idx & 127;
        float s = 0.f;
        #pragma unroll
        for (int uu = 0; uu < 8; ++uu) s += part[uu * 1024 + r * 128 + f];
        pb[f * 24 + 8 + r] = s * (1.f / fmaxf(cnt[r], 1.f));
    }
    __syncthreads();
    // ---- sweep rel1 ----
    {
        float acc[32];
        #pragma unroll
        for (int i = 0; i < 32; ++i) acc[i] = 0.f;
        #pragma unroll 8
        for (int ii = 0; ii < 16; ++ii) {
            int i = u * 16 + ii;
            float4 h4 = *(const float4*)&Hb[(size_t)i * 128 + q * 4];
            float hc[4] = {h4.x, h4.y, h4.z, h4.w};
            float4 ma = *(const float4*)&maskM[i * 16 + 8];
            float4 mb = *(const float4*)&maskM[i * 16 + 12];
            float mr[8] = {ma.x, ma.y, ma.z, ma.w, mb.x, mb.y, mb.z, mb.w};
            #pragma unroll
            for (int r = 0; r < 8; ++r)
                #pragma unroll
                for (int c = 0; c < 4; ++c)
                    acc[r * 4 + c] = fmaf(mr[r], hc[c], acc[r * 4 + c]);
        }
        #pragma unroll
        for (int i = 0; i < 32; ++i) acc[i] += __shfl_down(acc[i], 32, 64);
        if ((t & 63) < 32)
            #pragma unroll
            for (int r = 0; r < 8; ++r)
                *(float4*)&part[w * 1024 + r * 128 + q * 4] =
                    make_float4(acc[r*4+0], acc[r*4+1], acc[r*4+2], acc[r*4+3]);
    }
    __syncthreads();
    #pragma unroll
    for (int e = 0; e < 2; ++e) {   // combine -> pb mean1; root rows -> pb
        int idx = e * 512 + t;
        int r = idx >> 7, f = idx & 127;
        float s = 0.f;
        #pragma unroll
        for (int uu = 0; uu < 8; ++uu) s += part[uu * 1024 + r * 128 + f];
        pb[f * 24 + 16 + r] = s * (1.f / fmaxf(cnt[8 + r], 1.f));
        pb[f * 24 + r] = Hb[(size_t)(j0 + r) * 128 + f];
    }
    __syncthreads();
    // phase B: K=128, thread covers k in [u*8, u*8+8)
    {
        float acc[32];
        #pragma unroll
        for (int i = 0; i < 32; ++i) acc[i] = 0.f;
        #pragma unroll 4
        for (int kk = 0; kk < 8; ++kk) {
            int k = u * 8 + kk;
            float4 wr = *(const float4*)&Wroot[(size_t)k * 128 + q * 4];
            float4 wa = *(const float4*)&W0[(size_t)k * 128 + q * 4];
            float4 wb = *(const float4*)&W1[(size_t)k * 128 + q * 4];
            float wrc[4] = {wr.x, wr.y, wr.z, wr.w};
            float wac[4] = {wa.x, wa.y, wa.z, wa.w};
            float wbc[4] = {wb.x, wb.y, wb.z, wb.w};
            float4 h0 = *(const float4*)&pb[k * 24];
            float4 h1 = *(const float4*)&pb[k * 24 + 4];
            float4 p0 = *(const float4*)&pb[k * 24 + 8];
            float4 p1 = *(const float4*)&pb[k * 24 + 12];
            float4 q0 = *(const float4*)&pb[k * 24 + 16];
            float4 q1 = *(const float4*)&pb[k * 24 + 20];
            float hr[8]  = {h0.x, h0.y, h0.z, h0.w, h1.x, h1.y, h1.z, h1.w};
            float m0r[8] = {p0.x, p0.y, p0.z, p0.w, p1.x, p1.y, p1.z, p1.w};
            float m1r[8] = {q0.x, q0.y, q0.z, q0.w, q1.x, q1.y, q1.z, q1.w};
            #pragma unroll
            for (int r = 0; r < 8; ++r)
                #pragma unroll
                for (int c = 0; c < 4; ++c) {
                    float v = acc[r * 4 + c];
                    v = fmaf(hr[r],  wrc[c], v);
                    v = fmaf(m0r[r], wac[c], v);
                    v = fmaf(m1r[r], wbc[c], v);
                    acc[r * 4 + c] = v;
                }
        }
        #pragma unroll
        for (int i = 0; i < 32; ++i) acc[i] += __shfl_down(acc[i], 32, 64);
        if ((t & 63) < 32)
            #pragma unroll
            for (int r = 0; r < 8; ++r)
                *(float4*)&part[w * 1024 + r * 128 + q * 4] =
                    make_float4(acc[r*4+0], acc[r*4+1], acc[r*4+2], acc[r*4+3]);
    }
    __syncthreads();
    #pragma unroll
    for (int e = 0; e < 2; ++e) {
        int idx = e * 512 + t;
        int r = idx >> 7, f = idx & 127;
        float s = bias[f];
        #pragma unroll
        for (int uu = 0; uu < 8; ++uu) s += part[uu * 1024 + r * 128 + f];
        H2[(size_t)(b * 256 + j0 + r) * 128 + f] = s;
    }
}

// ---------------------------------------------------------------------------
// k_gcn2: |A|-aggregation + LayerNorm + 2-layer MLP + H-update. 8 rows/block.
// ---------------------------------------------------------------------------
__global__ __launch_bounds__(512, 2) void k_gcn2(
        const float* __restrict__ A, const float* __restrict__ H2,
        const float* __restrict__ g, const float* __restrict__ bta,
        const float* __restrict__ law, const float* __restrict__ lab,
        const float* __restrict__ lbw, const float* __restrict__ lbb,
        float* __restrict__ H) {
    const int b  = blockIdx.x >> 5;
    const int i0 = (blockIdx.x & 31) * 8;
    const int t = threadIdx.x, q = t & 31, u = t >> 5, w = t >> 6;
    __shared__ __align__(16) float part[8192];   // [8w][8r][128f]
    __shared__ __align__(16) float absA[2048];   // [256 j][8 r]
    __shared__ __align__(16) float xq[1024];     // [k][r]
    __shared__ __align__(16) float uq[1024];     // [k][r]
    __shared__ float red[32];
    __shared__ float mi[16];
    const float* Ab  = A + (size_t)b * 65536;
    const float* H2b = H2 + (size_t)b * 32768;

    if (t < 256) {
        #pragma unroll
        for (int r = 0; r < 8; ++r)
            absA[t * 8 + r] = fabsf(Ab[(size_t)(i0 + r) * 256 + t]);
    }
    __syncthreads();
    // phase A: thread sweeps j in [u*16, u*16+16)
    {
        float acc[32];
        #pragma unroll
        for (int i = 0; i < 32; ++i) acc[i] = 0.f;
        #pragma unroll 8
        for (int jj = 0; jj < 16; ++jj) {
            int j = u * 16 + jj;
            float4 h4 = *(const float4*)&H2b[(size_t)j * 128 + q * 4];
            float hc[4] = {h4.x, h4.y, h4.z, h4.w};
            float4 aa = *(const float4*)&absA[j * 8];
            float4 ab = *(const float4*)&absA[j * 8 + 4];
            float ar[8] = {aa.x, aa.y, aa.z, aa.w, ab.x, ab.y, ab.z, ab.w};
            #pragma unroll
            for (int r = 0; r < 8; ++r)
                #pragma unroll
                for (int c = 0; c < 4; ++c)
                    acc[r * 4 + c] = fmaf(ar[r], hc[c], acc[r * 4 + c]);
        }
        #pragma unroll
        for (int i = 0; i < 32; ++i) acc[i] += __shfl_down(acc[i], 32, 64);
        if ((t & 63) < 32)
            #pragma unroll
            for (int r = 0; r < 8; ++r)
                *(float4*)&part[w * 1024 + r * 128 + q * 4] =
                    make_float4(acc[r*4+0], acc[r*4+1], acc[r*4+2], acc[r*4+3]);
    }
    __syncthreads();
    // combine + per-row LN stats; thread owns (r, f) for e=0 (rows 0-3), e=1 (4-7)
    float xv[2];
    const int fof = t & 127;
    #pragma unroll
    for (int e = 0; e < 2; ++e) {
        int idx = e * 512 + t;
        int r = idx >> 7;
        float s = 0.f;
        #pragma unroll
        for (int uu = 0; uu < 8; ++uu) s += part[uu * 1024 + r * 128 + fof];
        xv[e] = s;
        float sw = s, s2 = s * s;
        #pragma unroll
        for (int o = 32; o > 0; o >>= 1) {
            sw += __shfl_down(sw, o, 64);
            s2 += __shfl_down(s2, o, 64);
        }
        if ((t & 63) == 0) {
            int half = (t >> 6) & 1;
            red[r * 4 + half * 2]     = sw;
            red[r * 4 + half * 2 + 1] = s2;
        }
    }
    __syncthreads();
    if (t < 8) {
        float s  = red[t * 4]     + red[t * 4 + 2];
        float s2 = red[t * 4 + 1] + red[t * 4 + 3];
        float m = s * (1.f / 128.f);
        float v = s2 * (1.f / 128.f) - m * m;
        mi[t * 2] = m;
        mi[t * 2 + 1] = rsqrtf(v + 1e-5f);
    }
    __syncthreads();
    {
        float gf = g[fof], bf = bta[fof];
        #pragma unroll
        for (int e = 0; e < 2; ++e) {
            int r = ((e * 512 + t) >> 7);
            xq[fof * 8 + r] = fmaxf((xv[e] - mi[r * 2]) * mi[r * 2 + 1] * gf + bf, 0.f);
        }
    }
    __syncthreads();
    // MLP layer A: K=128, thread covers k in [u*8, u*8+8)
    {
        float acc[32];
        #pragma unroll
        for (int i = 0; i < 32; ++i) acc[i] = 0.f;
        #pragma unroll
        for (int kk = 0; kk < 8; ++kk) {
            int k = u * 8 + kk;
            float4 w4 = *(const float4*)&law[(size_t)k * 128 + q * 4];
            float wc[4] = {w4.x, w4.y, w4.z, w4.w};
            float4 xa = *(const float4*)&xq[k * 8];
            float4 xb = *(const float4*)&xq[k * 8 + 4];
            float xr[8] = {xa.x, xa.y, xa.z, xa.w, xb.x, xb.y, xb.z, xb.w};
            #pragma unroll
            for (int r = 0; r < 8; ++r)
                #pragma unroll
                for (int c = 0; c < 4; ++c)
                    acc[r * 4 + c] = fmaf(xr[r], wc[c], acc[r * 4 + c]);
        }
        #pragma unroll
        for (int i = 0; i < 32; ++i) acc[i] += __shfl_down(acc[i], 32, 64);
        if ((t & 63) < 32)
            #pragma unroll
            for (int r = 0; r < 8; ++r)
                *(float4*)&part[w * 1024 + r * 128 + q * 4] =
                    make_float4(acc[r*4+0], acc[r*4+1], acc[r*4+2], acc[r*4+3]);
    }
    __syncthreads();
    #pragma unroll
    for (int e = 0; e < 2; ++e) {
        int idx = e * 512 + t;
        int r = idx >> 7, f = idx & 127;
        float s = lab[f];
        #pragma unroll
        for (int uu = 0; uu < 8; ++uu) s += part[uu * 1024 + r * 128 + f];
        uq[f * 8 + r] = fmaxf(s, 0.f);
    }
    __syncthreads();
    // MLP layer B: K=128
    {
        float acc[32];
        #pragma unroll
        for (int i = 0; i < 32; ++i) acc[i] = 0.f;
        #pragma unroll
        for (int kk = 0; kk < 8; ++kk) {
            int k = u * 8 + kk;
            float4 w4 = *(const float4*)&lbw[(size_t)k * 128 + q * 4];
            float wc[4] = {w4.x, w4.y, w4.z, w4.w};
            float4 xa = *(const float4*)&uq[k * 8];
            float4 xb = *(const float4*)&uq[k * 8 + 4];
            float xr[8] = {xa.x, xa.y, xa.z, xa.w, xb.x, xb.y, xb.z, xb.w};
            #pragma unroll
            for (int r = 0; r < 8; ++r)
                #pragma unroll
                for (int c = 0; c < 4; ++c)
                    acc[r * 4 + c] = fmaf(xr[r], wc[c], acc[r * 4 + c]);
        }
        #pragma unroll
        for (int i = 0; i < 32; ++i) acc[i] += __shfl_down(acc[i], 32, 64);
        if ((t & 63) < 32)
            #pragma unroll
            for (int r = 0; r < 8; ++r)
                *(float4*)&part[w * 1024 + r * 128 + q * 4] =
                    make_float4(acc[r*4+0], acc[r*4+1], acc[r*4+2], acc[r*4+3]);
    }
    __syncthreads();
    #pragma unroll
    for (int e = 0; e < 2; ++e) {
        int idx = e * 512 + t;
        int r = idx >> 7, f = idx & 127;
        float s = lbb[f];
        #pragma unroll
        for (int uu = 0; uu < 8; ++uu) s += part[uu * 1024 + r * 128 + f];
        size_t hidx = (size_t)(b * 256 + i0 + r) * 128 + f;
        H[hidx] = s + H[hidx];
    }
}

// ---------------------------------------------------------------------------
// k_deepset: phi (128->256->256 relu) + masked pooling. 8 rows/block,
// grid 256. q = t&63 (f-quad of 256), u = t>>6 (8 K-slices = waves).
// Partials combined in two 4-row passes (part 32 KB).
// ---------------------------------------------------------------------------
__global__ __launch_bounds__(512, 2) void k_deepset(
        const float* __restrict__ H, const float* __restrict__ hm,
        const float* __restrict__ w1, const float* __restrict__ b1,
        const float* __restrict__ w2, const float* __restrict__ b2,
        float* __restrict__ hsum, float* __restrict__ asum) {
    const int r0 = blockIdx.x * 8;
    const int b  = blockIdx.x >> 5;
    const int t  = threadIdx.x, q = t & 63, u = t >> 6;
    __shared__ __align__(16) float part[8192];   // [8u][4r][256f]
    __shared__ __align__(16) float ph2[2048];    // [256 k][8 r]
    __shared__ __align__(16) float hraw[1024];   // [128 k][8 r]
    __shared__ float hmv[8];
    #pragma unroll
    for (int e = 0; e < 2; ++e) {
        int idx = e * 512 + t;
        int r = idx >> 7, k = idx & 127;
        hraw[k * 8 + r] = H[(size_t)(r0 + r) * 128 + k];
    }
    if (t < 8) hmv[t] = hm[r0 + t];
    __syncthreads();
    // L1: K=128, thread covers k in [u*16, u*16+16)
    float acc[32];
    #pragma unroll
    for (int i = 0; i < 32; ++i) acc[i] = 0.f;
    #pragma unroll 8
    for (int kk = 0; kk < 16; ++kk) {
        int k = u * 16 + kk;
        float4 w4 = *(const float4*)&w1[(size_t)k * 256 + q * 4];
        float wc[4] = {w4.x, w4.y, w4.z, w4.w};
        float4 ha = *(const float4*)&hraw[k * 8];
        float4 hb = *(const float4*)&hraw[k * 8 + 4];
        float hr[8] = {ha.x, ha.y, ha.z, ha.w, hb.x, hb.y, hb.z, hb.w};
        #pragma unroll
        for (int r = 0; r < 8; ++r)
            #pragma unroll
            for (int c = 0; c < 4; ++c)
                acc[r * 4 + c] = fmaf(hr[r], wc[c], acc[r * 4 + c]);
    }
    #pragma unroll
    for (int pass = 0; pass < 2; ++pass) {   // combine rows 0-3 then 4-7
        #pragma unroll
        for (int r = 0; r < 4; ++r)
            *(float4*)&part[u * 1024 + r * 256 + q * 4] =
                make_float4(acc[(pass*4+r)*4+0], acc[(pass*4+r)*4+1],
                            acc[(pass*4+r)*4+2], acc[(pass*4+r)*4+3]);
        __syncthreads();
        #pragma unroll
        for (int e = 0; e < 2; ++e) {
            int idx = e * 512 + t;
            int r = idx >> 8, f = idx & 255;
            float s = b1[f];
            #pragma unroll
            for (int uu = 0; uu < 8; ++uu) s += part[uu * 1024 + r * 256 + f];
            ph2[f * 8 + pass * 4 + r] = fmaxf(s, 0.f);
        }
        __syncthreads();
    }
    // L2: K=256, thread covers k in [u*32, u*32+32)
    float a2[32];
    #pragma unroll
    for (int i = 0; i < 32; ++i) a2[i] = 0.f;
    #pragma unroll 8
    for (int kk = 0; kk < 32; ++kk) {
        int k = u * 32 + kk;
        float4 w4 = *(const float4*)&w2[(size_t)k * 256 + q * 4];
        float wc[4] = {w4.x, w4.y, w4.z, w4.w};
        float4 pa = *(const float4*)&ph2[k * 8];
        float4 pbv = *(const float4*)&ph2[k * 8 + 4];
        float pr[8] = {pa.x, pa.y, pa.z, pa.w, pbv.x, pbv.y, pbv.z, pbv.w};
        #pragma unroll
        for (int r = 0; r < 8; ++r)
            #pragma unroll
            for (int c = 0; c < 4; ++c)
                a2[r * 4 + c] = fmaf(pr[r], wc[c], a2[r * 4 + c]);
    }
    __syncthreads();   // ph2 reads done; reuse ph2 as pooled-output buffer
    #pragma unroll
    for (int pass = 0; pass < 2; ++pass) {
        #pragma unroll
        for (int r = 0; r < 4; ++r)
            *(float4*)&part[u * 1024 + r * 256 + q * 4] =
                make_float4(a2[(pass*4+r)*4+0], a2[(pass*4+r)*4+1],
                            a2[(pass*4+r)*4+2], a2[(pass*4+r)*4+3]);
        __syncthreads();
        #pragma unroll
        for (int e = 0; e < 2; ++e) {
            int idx = e * 512 + t;
            int r = idx >> 8, f = idx & 255;
            float s = 0.f;
            #pragma unroll
            for (int uu = 0; uu < 8; ++uu) s += part[uu * 1024 + r * 256 + f];
            ph2[f * 8 + pass * 4 + r] = s;
        }
        __syncthreads();
    }
    if (t < 256) {   // final: +b2, relu, masked pool (f = t)
        float bb = b2[t];
        float hp = 0.f, sp = 0.f;
        #pragma unroll
        for (int r = 0; r < 8; ++r) {
            float p = fmaxf(ph2[t * 8 + r] + bb, 0.f);
            sp += p;
            hp = fmaf(p, hmv[r], hp);
        }
        atomicAdd(&hsum[b * 256 + t], hp);
        atomicAdd(&asum[b * 256 + t], sp - hp);
    }
}

// ---------------------------------------------------------------------------
// k_rho: out[b] = 0.5 + 0.5*tanh(rho(home)-rho(away)); b2 cancels.
// ---------------------------------------------------------------------------
__global__ __launch_bounds__(256) void k_rho(const float* __restrict__ hsum,
        const float* __restrict__ asum,
        const float* __restrict__ w1, const float* __restrict__ b1,
        const float* __restrict__ w2, const float* __restrict__ b2,
        float* __restrict__ out) {
    const int bIdx = blockIdx.x;
    const int t = threadIdx.x, q = t & 31, u = t >> 5;
    __shared__ __align__(16) float part[2048];
    __shared__ __align__(16) float sv[512];
    __shared__ float wsv[2];
    sv[t] = hsum[bIdx * 256 + t];
    sv[256 + t] = asum[bIdx * 256 + t];
    __syncthreads();
    float aH[4] = {0.f, 0.f, 0.f, 0.f}, aA[4] = {0.f, 0.f, 0.f, 0.f};
    #pragma unroll 8
    for (int kk = 0; kk < 32; ++kk) {
        int k = u * 32 + kk;
        float4 w4 = *(const float4*)&w1[(size_t)k * 128 + q * 4];
        float sh = sv[k], sa = sv[256 + k];
        aH[0] = fmaf(sh, w4.x, aH[0]); aA[0] = fmaf(sa, w4.x, aA[0]);
        aH[1] = fmaf(sh, w4.y, aH[1]); aA[1] = fmaf(sa, w4.y, aA[1]);
        aH[2] = fmaf(sh, w4.z, aH[2]); aA[2] = fmaf(sa, w4.z, aA[2]);
        aH[3] = fmaf(sh, w4.w, aH[3]); aA[3] = fmaf(sa, w4.w, aA[3]);
    }
    *(float4*)&part[u * 256 + q * 4]       = make_float4(aH[0], aH[1], aH[2], aH[3]);
    *(float4*)&part[u * 256 + 128 + q * 4] = make_float4(aA[0], aA[1], aA[2], aA[3]);
    __syncthreads();
    if (t < 64) {
        int vec = t >> 5, fq = t & 31;
        float4 s = make_float4(0.f, 0.f, 0.f, 0.f);
        #pragma unroll
        for (int uu = 0; uu < 8; ++uu) {
            float4 p = *(const float4*)&part[uu * 256 + vec * 128 + fq * 4];
            s.x += p.x; s.y += p.y; s.z += p.z; s.w += p.w;
        }
        float4 bb = *(const float4*)&b1[fq * 4];
        float4 w2q = *(const float4*)&w2[fq * 4];
        float p = fmaxf(s.x + bb.x, 0.f) * w2q.x
                + fmaxf(s.y + bb.y, 0.f) * w2q.y
                + fmaxf(s.z + bb.z, 0.f) * w2q.z
                + fmaxf(s.w + bb.w, 0.f) * w2q.w;
        #pragma unroll
        for (int o = 16; o > 0; o >>= 1) p += __shfl_down(p, o, 32);
        if ((t & 31) == 0) wsv[vec] = p;
    }
    __syncthreads();
    if (t == 0) out[bIdx] = 0.5f + 0.5f * tanhf(wsv[0] - wsv[1]);
}

// ---------------------------------------------------------------------------
extern "C" void kernel_launch(void* const* d_in, const int* in_sizes, int n_in,
                              void* d_out, int out_size, void* d_ws, size_t ws_size,
                              hipStream_t stream) {
    const float* A         = (const float*)d_in[0];
    const float* X         = (const float*)d_in[1];
    const float* home_mask = (const float*)d_in[2];
    const float* emb1_w    = (const float*)d_in[3];
    const float* emb1_b    = (const float*)d_in[4];
    const float* emb2_w    = (const float*)d_in[5];
    const float* emb2_b    = (const float*)d_in[6];
    const float* rgcn_w[2]    = { (const float*)d_in[7],  (const float*)d_in[14] };
    const float* rgcn_root[2] = { (const float*)d_in[8],  (const float*)d_in[15] };
    const float* rgcn_bias[2] = { (const float*)d_in[9],  (const float*)d_in[16] };
    const float* lina_w[2]    = { (const float*)d_in[10], (const float*)d_in[17] };
    const float* lina_b[2]    = { (const float*)d_in[11], (const float*)d_in[18] };
    const float* linb_w[2]    = { (const float*)d_in[12], (const float*)d_in[19] };
    const float* linb_b[2]    = { (const float*)d_in[13], (const float*)d_in[20] };
    const float* norm_g  = (const float*)d_in[21];
    const float* norm_b  = (const float*)d_in[22];
    const float* phi_w1  = (const float*)d_in[23];
    const float* phi_b1  = (const float*)d_in[24];
    const float* phi_w2  = (const float*)d_in[25];
    const float* phi_b2  = (const float*)d_in[26];
    const float* rho_w1  = (const float*)d_in[27];
    const float* rho_b1  = (const float*)d_in[28];
    const float* rho_w2  = (const float*)d_in[29];
    const float* rho_b2  = (const float*)d_in[30];
    float* out = (float*)d_out;

    float* ws   = (float*)d_ws;
    float* H    = ws;               // 262144
    float* H2   = ws + 262144;      // 262144
    float* hsum = ws + 524288;      // 2048
    float* asum = ws + 526336;      // 2048 (contiguous with hsum)

    k_embed<<<256, 512, 0, stream>>>(X, emb1_w, emb1_b, emb2_w, emb2_b, H, hsum);

    for (int it = 0; it < 2; ++it) {
        k_gcn1<<<256, 512, 0, stream>>>(A, H, rgcn_w[it], rgcn_root[it],
                                        rgcn_bias[it], H2);
        k_gcn2<<<256, 512, 0, stream>>>(A, H2, norm_g, norm_b,
                                        lina_w[it], lina_b[it],
                                        linb_w[it], linb_b[it], H);
    }

    k_deepset<<<256, 512, 0, stream>>>(H, home_mask, phi_w1, phi_b1,
                                       phi_w2, phi_b2, hsum, asum);
    k_rho<<<NB, 256, 0, stream>>>(hsum, asum, rho_w1, rho_b1, rho_w2, rho_b2, out);
}

// Round 5
// 197.513 us; speedup vs baseline: 1.0457x; 1.0457x over previous
//
#include <hip/hip_runtime.h>
#include <math.h>

// Shapes: B=8, N=256, NID=64, V=GH=128, PHI=256, RHO=128
#define NB 8

// ---------------------------------------------------------------------------
// 128-f kernels: 1024 threads, grid 256 (1 block/CU, 16 waves), 8 rows/block.
// q=t&31 (f-quad), h=(t>>5)&1 (row-half: rows h*4..h*4+3), u=t>>6 (wave =
// K-slice, 16 slices). Weight loads broadcast across half-waves. Partials:
// part[16u][4r][128f] = 32 KB, combined in two row-half passes.
// Rationale (R2-R4 data): effective L2/L3 BW for replicated reads scales with
// waves/CU (7.8 TB/s @16w, 3.9 @8w); this config = 16 waves AND halved traffic.
// ---------------------------------------------------------------------------

// k_embed: H = relu(X@w1+b1)@w2+b2.
__global__ __launch_bounds__(1024, 4) void k_embed(const float* __restrict__ X,
        const float* __restrict__ w1, const float* __restrict__ b1,
        const float* __restrict__ w2, const float* __restrict__ b2,
        float* __restrict__ H, float* __restrict__ pools) {
    const int r0 = blockIdx.x * 8;
    const int t = threadIdx.x, q = t & 31, h = (t >> 5) & 1, u = t >> 6;
    __shared__ __align__(16) float part[8192];   // [16u][4r][128f]
    __shared__ __align__(16) float xq[512];      // [64k][8r]
    __shared__ __align__(16) float h1q[1024];    // [128k][8r]
    if (blockIdx.x < 4) pools[blockIdx.x * 1024 + t] = 0.f;
    if (t < 512) {
        int r = t >> 6, k = t & 63;
        xq[k * 8 + r] = X[(size_t)(r0 + r) * 64 + k];
    }
    __syncthreads();
    float acc[16];
    // ---- L1: K=64, k in [u*4, u*4+4) ----
    #pragma unroll
    for (int i = 0; i < 16; ++i) acc[i] = 0.f;
    #pragma unroll
    for (int kk = 0; kk < 4; ++kk) {
        int k = u * 4 + kk;
        float4 w4 = *(const float4*)&w1[(size_t)k * 128 + q * 4];
        float wc[4] = {w4.x, w4.y, w4.z, w4.w};
        float4 x4 = *(const float4*)&xq[k * 8 + h * 4];
        float xr[4] = {x4.x, x4.y, x4.z, x4.w};
        #pragma unroll
        for (int r = 0; r < 4; ++r)
            #pragma unroll
            for (int c = 0; c < 4; ++c)
                acc[r * 4 + c] = fmaf(xr[r], wc[c], acc[r * 4 + c]);
    }
    #pragma unroll
    for (int p = 0; p < 2; ++p) {
        if (h == p)
            #pragma unroll
            for (int r = 0; r < 4; ++r)
                *(float4*)&part[u * 512 + r * 128 + q * 4] =
                    make_float4(acc[r*4+0], acc[r*4+1], acc[r*4+2], acc[r*4+3]);
        __syncthreads();
        if (t < 512) {
            int r = t >> 7, f = t & 127, row = p * 4 + r;
            float s = b1[f];
            #pragma unroll
            for (int uu = 0; uu < 16; ++uu) s += part[uu * 512 + r * 128 + f];
            h1q[f * 8 + row] = fmaxf(s, 0.f);
        }
        __syncthreads();
    }
    // ---- L2: K=128, k in [u*8, u*8+8) ----
    #pragma unroll
    for (int i = 0; i < 16; ++i) acc[i] = 0.f;
    #pragma unroll
    for (int kk = 0; kk < 8; ++kk) {
        int k = u * 8 + kk;
        float4 w4 = *(const float4*)&w2[(size_t)k * 128 + q * 4];
        float wc[4] = {w4.x, w4.y, w4.z, w4.w};
        float4 x4 = *(const float4*)&h1q[k * 8 + h * 4];
        float xr[4] = {x4.x, x4.y, x4.z, x4.w};
        #pragma unroll
        for (int r = 0; r < 4; ++r)
            #pragma unroll
            for (int c = 0; c < 4; ++c)
                acc[r * 4 + c] = fmaf(xr[r], wc[c], acc[r * 4 + c]);
    }
    #pragma unroll
    for (int p = 0; p < 2; ++p) {
        if (h == p)
            #pragma unroll
            for (int r = 0; r < 4; ++r)
                *(float4*)&part[u * 512 + r * 128 + q * 4] =
                    make_float4(acc[r*4+0], acc[r*4+1], acc[r*4+2], acc[r*4+3]);
        __syncthreads();
        if (t < 512) {
            int r = t >> 7, f = t & 127, row = p * 4 + r;
            float s = b2[f];
            #pragma unroll
            for (int uu = 0; uu < 16; ++uu) s += part[uu * 512 + r * 128 + f];
            H[(size_t)(r0 + row) * 128 + f] = s;
        }
        __syncthreads();
    }
}

// ---------------------------------------------------------------------------
// k_gcn1: relation-mean aggregation + RGCN 3-matrix linear. Block = (b, 8 j).
// Two i-sweeps (rel0, rel1); weights/H direct from L2.
// ---------------------------------------------------------------------------
__global__ __launch_bounds__(1024, 4) void k_gcn1(
        const float* __restrict__ A, const float* __restrict__ H,
        const float* __restrict__ Wrel, const float* __restrict__ Wroot,
        const float* __restrict__ bias, float* __restrict__ H2) {
    const int b  = blockIdx.x >> 5;
    const int j0 = (blockIdx.x & 31) * 8;
    const int t = threadIdx.x, q = t & 31, h = (t >> 5) & 1, u = t >> 6;
    __shared__ __align__(16) float maskM[4096];  // [256 i][16] (8 m0 | 8 m1)
    __shared__ __align__(16) float part[8192];   // [16u][4r][128f]
    __shared__ __align__(16) float pb[3072];     // [128 k][24] root8|m0_8|m1_8
    __shared__ float cntp[512];
    __shared__ float cnt[16];
    const float* Ab = A + (size_t)b * 65536;
    const float* Hb = H + (size_t)b * 32768;
    const float* W0 = Wrel;
    const float* W1 = Wrel + 16384;

    if (t < 256) {   // masks: thread t owns row i=t, 8 columns
        float4 a0 = *(const float4*)(Ab + (size_t)t * 256 + j0);
        float4 a1 = *(const float4*)(Ab + (size_t)t * 256 + j0 + 4);
        float av[8] = {a0.x, a0.y, a0.z, a0.w, a1.x, a1.y, a1.z, a1.w};
        #pragma unroll
        for (int j = 0; j < 8; ++j) {
            maskM[t * 16 + j]     = (av[j] < 0.f) ? 1.f : 0.f;
            maskM[t * 16 + 8 + j] = (av[j] > 0.f) ? 1.f : 0.f;
        }
    }
    __syncthreads();
    if (t < 512) {   // count partials: 32 chunks x 16 slots
        int chunk = t >> 4, slot = t & 15;
        float c = 0.f;
        #pragma unroll
        for (int qq = 0; qq < 8; ++qq) c += maskM[(chunk * 8 + qq) * 16 + slot];
        cntp[slot * 32 + chunk] = c;
    }
    __syncthreads();
    if (t < 16) {    // concurrent with rel0 sweep; ordered by next barrier
        float s = 0.f;
        #pragma unroll
        for (int c = 0; c < 32; ++c) s += cntp[t * 32 + c];
        cnt[t] = s;
    }
    float acc[16];
    // ---- sweep rel0: i in [u*16, u*16+16) ----
    #pragma unroll
    for (int i = 0; i < 16; ++i) acc[i] = 0.f;
    #pragma unroll 8
    for (int ii = 0; ii < 16; ++ii) {
        int i = u * 16 + ii;
        float4 h4 = *(const float4*)&Hb[(size_t)i * 128 + q * 4];
        float hc[4] = {h4.x, h4.y, h4.z, h4.w};
        float4 m4 = *(const float4*)&maskM[i * 16 + h * 4];
        float mr[4] = {m4.x, m4.y, m4.z, m4.w};
        #pragma unroll
        for (int r = 0; r < 4; ++r)
            #pragma unroll
            for (int c = 0; c < 4; ++c)
                acc[r * 4 + c] = fmaf(mr[r], hc[c], acc[r * 4 + c]);
    }
    #pragma unroll
    for (int p = 0; p < 2; ++p) {
        if (h == p)
            #pragma unroll
            for (int r = 0; r < 4; ++r)
                *(float4*)&part[u * 512 + r * 128 + q * 4] =
                    make_float4(acc[r*4+0], acc[r*4+1], acc[r*4+2], acc[r*4+3]);
        __syncthreads();
        if (t < 512) {
            int r = t >> 7, f = t & 127, row = p * 4 + r;
            float s = 0.f;
            #pragma unroll
            for (int uu = 0; uu < 16; ++uu) s += part[uu * 512 + r * 128 + f];
            pb[f * 24 + 8 + row] = s * (1.f / fmaxf(cnt[row], 1.f));
        }
        __syncthreads();
    }
    // ---- sweep rel1 ----
    #pragma unroll
    for (int i = 0; i < 16; ++i) acc[i] = 0.f;
    #pragma unroll 8
    for (int ii = 0; ii < 16; ++ii) {
        int i = u * 16 + ii;
        float4 h4 = *(const float4*)&Hb[(size_t)i * 128 + q * 4];
        float hc[4] = {h4.x, h4.y, h4.z, h4.w};
        float4 m4 = *(const float4*)&maskM[i * 16 + 8 + h * 4];
        float mr[4] = {m4.x, m4.y, m4.z, m4.w};
        #pragma unroll
        for (int r = 0; r < 4; ++r)
            #pragma unroll
            for (int c = 0; c < 4; ++c)
                acc[r * 4 + c] = fmaf(mr[r], hc[c], acc[r * 4 + c]);
    }
    #pragma unroll
    for (int p = 0; p < 2; ++p) {
        if (h == p)
            #pragma unroll
            for (int r = 0; r < 4; ++r)
                *(float4*)&part[u * 512 + r * 128 + q * 4] =
                    make_float4(acc[r*4+0], acc[r*4+1], acc[r*4+2], acc[r*4+3]);
        __syncthreads();
        if (t < 512) {
            int r = t >> 7, f = t & 127, row = p * 4 + r;
            float s = 0.f;
            #pragma unroll
            for (int uu = 0; uu < 16; ++uu) s += part[uu * 512 + r * 128 + f];
            pb[f * 24 + 16 + row] = s * (1.f / fmaxf(cnt[8 + row], 1.f));
        } else {   // t>=512: root rows -> pb (idx in [p*512, p*512+512))
            int idx = p * 512 + (t - 512);
            int r8 = idx >> 7, f2 = idx & 127;
            pb[f2 * 24 + r8] = Hb[(size_t)(j0 + r8) * 128 + f2];
        }
        __syncthreads();
    }
    // ---- phase B: K=128, k in [u*8, u*8+8) ----
    #pragma unroll
    for (int i = 0; i < 16; ++i) acc[i] = 0.f;
    #pragma unroll
    for (int kk = 0; kk < 8; ++kk) {
        int k = u * 8 + kk;
        float4 wr = *(const float4*)&Wroot[(size_t)k * 128 + q * 4];
        float4 wa = *(const float4*)&W0[(size_t)k * 128 + q * 4];
        float4 wb = *(const float4*)&W1[(size_t)k * 128 + q * 4];
        float wrc[4] = {wr.x, wr.y, wr.z, wr.w};
        float wac[4] = {wa.x, wa.y, wa.z, wa.w};
        float wbc[4] = {wb.x, wb.y, wb.z, wb.w};
        float4 hv = *(const float4*)&pb[k * 24 + h * 4];
        float4 p0 = *(const float4*)&pb[k * 24 + 8 + h * 4];
        float4 p1 = *(const float4*)&pb[k * 24 + 16 + h * 4];
        float hr[4]  = {hv.x, hv.y, hv.z, hv.w};
        float m0r[4] = {p0.x, p0.y, p0.z, p0.w};
        float m1r[4] = {p1.x, p1.y, p1.z, p1.w};
        #pragma unroll
        for (int r = 0; r < 4; ++r)
            #pragma unroll
            for (int c = 0; c < 4; ++c) {
                float v = acc[r * 4 + c];
                v = fmaf(hr[r],  wrc[c], v);
                v = fmaf(m0r[r], wac[c], v);
                v = fmaf(m1r[r], wbc[c], v);
                acc[r * 4 + c] = v;
            }
    }
    #pragma unroll
    for (int p = 0; p < 2; ++p) {
        if (h == p)
            #pragma unroll
            for (int r = 0; r < 4; ++r)
                *(float4*)&part[u * 512 + r * 128 + q * 4] =
                    make_float4(acc[r*4+0], acc[r*4+1], acc[r*4+2], acc[r*4+3]);
        __syncthreads();
        if (t < 512) {
            int r = t >> 7, f = t & 127, row = p * 4 + r;
            float s = bias[f];
            #pragma unroll
            for (int uu = 0; uu < 16; ++uu) s += part[uu * 512 + r * 128 + f];
            H2[(size_t)(b * 256 + j0 + row) * 128 + f] = s;
        }
        __syncthreads();
    }
}

// ---------------------------------------------------------------------------
// k_gcn2: |A|-aggregation + LayerNorm + 2-layer MLP + H-update. 8 rows/block.
// ---------------------------------------------------------------------------
__global__ __launch_bounds__(1024, 4) void k_gcn2(
        const float* __restrict__ A, const float* __restrict__ H2,
        const float* __restrict__ g, const float* __restrict__ bta,
        const float* __restrict__ law, const float* __restrict__ lab,
        const float* __restrict__ lbw, const float* __restrict__ lbb,
        float* __restrict__ H) {
    const int b  = blockIdx.x >> 5;
    const int i0 = (blockIdx.x & 31) * 8;
    const int t = threadIdx.x, q = t & 31, h = (t >> 5) & 1, u = t >> 6;
    __shared__ __align__(16) float part[8192];   // [16u][4r][128f]
    __shared__ __align__(16) float absA[2048];   // [256 j][8 r]
    __shared__ __align__(16) float xq[1024];     // [128 f][8 r]
    __shared__ __align__(16) float uq[1024];     // [128 f][8 r]
    __shared__ float red[32];
    __shared__ float mi[16];
    const float* Ab  = A + (size_t)b * 65536;
    const float* H2b = H2 + (size_t)b * 32768;

    if (t < 256) {
        #pragma unroll
        for (int r = 0; r < 8; ++r)
            absA[t * 8 + r] = fabsf(Ab[(size_t)(i0 + r) * 256 + t]);
    }
    __syncthreads();
    float acc[16];
    // ---- phase A: j in [u*16, u*16+16) ----
    #pragma unroll
    for (int i = 0; i < 16; ++i) acc[i] = 0.f;
    #pragma unroll 8
    for (int jj = 0; jj < 16; ++jj) {
        int j = u * 16 + jj;
        float4 h4 = *(const float4*)&H2b[(size_t)j * 128 + q * 4];
        float hc[4] = {h4.x, h4.y, h4.z, h4.w};
        float4 a4 = *(const float4*)&absA[j * 8 + h * 4];
        float ar[4] = {a4.x, a4.y, a4.z, a4.w};
        #pragma unroll
        for (int r = 0; r < 4; ++r)
            #pragma unroll
            for (int c = 0; c < 4; ++c)
                acc[r * 4 + c] = fmaf(ar[r], hc[c], acc[r * 4 + c]);
    }
    #pragma unroll
    for (int p = 0; p < 2; ++p) {
        if (h == p)
            #pragma unroll
            for (int r = 0; r < 4; ++r)
                *(float4*)&part[u * 512 + r * 128 + q * 4] =
                    make_float4(acc[r*4+0], acc[r*4+1], acc[r*4+2], acc[r*4+3]);
        __syncthreads();
        if (t < 512) {
            int r = t >> 7, f = t & 127, row = p * 4 + r;
            float s = 0.f;
            #pragma unroll
            for (int uu = 0; uu < 16; ++uu) s += part[uu * 512 + r * 128 + f];
            xq[f * 8 + row] = s;   // raw pre-LN
        }
        __syncthreads();
    }
    // ---- LN phase: thread owns (r = t>>7, f = t&127) ----
    {
        int r = t >> 7, f = t & 127;
        float x = xq[f * 8 + r];
        float sw = x, s2 = x * x;
        #pragma unroll
        for (int o = 32; o > 0; o >>= 1) {
            sw += __shfl_down(sw, o, 64);
            s2 += __shfl_down(s2, o, 64);
        }
        if ((t & 63) == 0) {
            int half = (t >> 6) & 1;
            red[r * 4 + half * 2]     = sw;
            red[r * 4 + half * 2 + 1] = s2;
        }
        __syncthreads();
        if (t < 8) {
            float s  = red[t * 4]     + red[t * 4 + 2];
            float ss = red[t * 4 + 1] + red[t * 4 + 3];
            float m = s * (1.f / 128.f);
            float v = ss * (1.f / 128.f) - m * m;
            mi[t * 2] = m;
            mi[t * 2 + 1] = rsqrtf(v + 1e-5f);
        }
        __syncthreads();
        xq[f * 8 + r] = fmaxf((x - mi[r * 2]) * mi[r * 2 + 1] * g[f] + bta[f], 0.f);
    }
    __syncthreads();
    // ---- MLP layer A: K=128, k in [u*8, u*8+8) ----
    #pragma unroll
    for (int i = 0; i < 16; ++i) acc[i] = 0.f;
    #pragma unroll
    for (int kk = 0; kk < 8; ++kk) {
        int k = u * 8 + kk;
        float4 w4 = *(const float4*)&law[(size_t)k * 128 + q * 4];
        float wc[4] = {w4.x, w4.y, w4.z, w4.w};
        float4 x4 = *(const float4*)&xq[k * 8 + h * 4];
        float xr[4] = {x4.x, x4.y, x4.z, x4.w};
        #pragma unroll
        for (int r = 0; r < 4; ++r)
            #pragma unroll
            for (int c = 0; c < 4; ++c)
                acc[r * 4 + c] = fmaf(xr[r], wc[c], acc[r * 4 + c]);
    }
    #pragma unroll
    for (int p = 0; p < 2; ++p) {
        if (h == p)
            #pragma unroll
            for (int r = 0; r < 4; ++r)
                *(float4*)&part[u * 512 + r * 128 + q * 4] =
                    make_float4(acc[r*4+0], acc[r*4+1], acc[r*4+2], acc[r*4+3]);
        __syncthreads();
        if (t < 512) {
            int r = t >> 7, f = t & 127, row = p * 4 + r;
            float s = lab[f];
            #pragma unroll
            for (int uu = 0; uu < 16; ++uu) s += part[uu * 512 + r * 128 + f];
            uq[f * 8 + row] = fmaxf(s, 0.f);
        }
        __syncthreads();
    }
    // ---- MLP layer B: K=128 ----
    #pragma unroll
    for (int i = 0; i < 16; ++i) acc[i] = 0.f;
    #pragma unroll
    for (int kk = 0; kk < 8; ++kk) {
        int k = u * 8 + kk;
        float4 w4 = *(const float4*)&lbw[(size_t)k * 128 + q * 4];
        float wc[4] = {w4.x, w4.y, w4.z, w4.w};
        float4 x4 = *(const float4*)&uq[k * 8 + h * 4];
        float xr[4] = {x4.x, x4.y, x4.z, x4.w};
        #pragma unroll
        for (int r = 0; r < 4; ++r)
            #pragma unroll
            for (int c = 0; c < 4; ++c)
                acc[r * 4 + c] = fmaf(xr[r], wc[c], acc[r * 4 + c]);
    }
    #pragma unroll
    for (int p = 0; p < 2; ++p) {
        if (h == p)
            #pragma unroll
            for (int r = 0; r < 4; ++r)
                *(float4*)&part[u * 512 + r * 128 + q * 4] =
                    make_float4(acc[r*4+0], acc[r*4+1], acc[r*4+2], acc[r*4+3]);
        __syncthreads();
        if (t < 512) {
            int r = t >> 7, f = t & 127, row = p * 4 + r;
            float s = lbb[f];
            #pragma unroll
            for (int uu = 0; uu < 16; ++uu) s += part[uu * 512 + r * 128 + f];
            size_t idx = (size_t)(b * 256 + i0 + row) * 128 + f;
            H[idx] = s + H[idx];
        }
        __syncthreads();
    }
}

// ---------------------------------------------------------------------------
// k_deepset: phi (128->256->256 relu) + masked pooling. 8 rows/block,
// grid 256, 1024 threads. q=t&63 (f-quad of 256), hw=(t>>6)&1 (row-half,
// per-wave), u=t>>7 (8 K-slices). part[8u][4r][256f] = 32 KB, two passes.
// ---------------------------------------------------------------------------
__global__ __launch_bounds__(1024, 4) void k_deepset(
        const float* __restrict__ H, const float* __restrict__ hm,
        const float* __restrict__ w1, const float* __restrict__ b1,
        const float* __restrict__ w2, const float* __restrict__ b2,
        float* __restrict__ hsum, float* __restrict__ asum) {
    const int r0 = blockIdx.x * 8;
    const int b  = blockIdx.x >> 5;
    const int t  = threadIdx.x, q = t & 63, hw = (t >> 6) & 1, u = t >> 7;
    __shared__ __align__(16) float part[8192];   // [8u][4r][256f]
    __shared__ __align__(16) float ph2[2048];    // [256 k][8 r]
    __shared__ __align__(16) float hraw[1024];   // [128 k][8 r]
    __shared__ float hmv[8];
    {
        int r = t >> 7, k = t & 127;
        hraw[k * 8 + r] = H[(size_t)(r0 + r) * 128 + k];
    }
    if (t < 8) hmv[t] = hm[r0 + t];
    __syncthreads();
    float acc[16];
    // ---- L1: K=128, k in [u*16, u*16+16) ----
    #pragma unroll
    for (int i = 0; i < 16; ++i) acc[i] = 0.f;
    #pragma unroll 8
    for (int kk = 0; kk < 16; ++kk) {
        int k = u * 16 + kk;
        float4 w4 = *(const float4*)&w1[(size_t)k * 256 + q * 4];
        float wc[4] = {w4.x, w4.y, w4.z, w4.w};
        float4 h4 = *(const float4*)&hraw[k * 8 + hw * 4];
        float hr[4] = {h4.x, h4.y, h4.z, h4.w};
        #pragma unroll
        for (int r = 0; r < 4; ++r)
            #pragma unroll
            for (int c = 0; c < 4; ++c)
                acc[r * 4 + c] = fmaf(hr[r], wc[c], acc[r * 4 + c]);
    }
    #pragma unroll
    for (int p = 0; p < 2; ++p) {
        if (hw == p)
            #pragma unroll
            for (int r = 0; r < 4; ++r)
                *(float4*)&part[u * 1024 + r * 256 + q * 4] =
                    make_float4(acc[r*4+0], acc[r*4+1], acc[r*4+2], acc[r*4+3]);
        __syncthreads();
        {
            int r = t >> 8, f = t & 255, row = p * 4 + r;
            float s = b1[f];
            #pragma unroll
            for (int uu = 0; uu < 8; ++uu) s += part[uu * 1024 + r * 256 + f];
            ph2[f * 8 + row] = fmaxf(s, 0.f);
        }
        __syncthreads();
    }
    // ---- L2: K=256, k in [u*32, u*32+32) ----
    #pragma unroll
    for (int i = 0; i < 16; ++i) acc[i] = 0.f;
    #pragma unroll 8
    for (int kk = 0; kk < 32; ++kk) {
        int k = u * 32 + kk;
        float4 w4 = *(const float4*)&w2[(size_t)k * 256 + q * 4];
        float wc[4] = {w4.x, w4.y, w4.z, w4.w};
        float4 p4 = *(const float4*)&ph2[k * 8 + hw * 4];
        float pr[4] = {p4.x, p4.y, p4.z, p4.w};
        #pragma unroll
        for (int r = 0; r < 4; ++r)
            #pragma unroll
            for (int c = 0; c < 4; ++c)
                acc[r * 4 + c] = fmaf(pr[r], wc[c], acc[r * 4 + c]);
    }
    __syncthreads();   // all ph2 reads done; reuse ph2 as output buffer
    #pragma unroll
    for (int p = 0; p < 2; ++p) {
        if (hw == p)
            #pragma unroll
            for (int r = 0; r < 4; ++r)
                *(float4*)&part[u * 1024 + r * 256 + q * 4] =
                    make_float4(acc[r*4+0], acc[r*4+1], acc[r*4+2], acc[r*4+3]);
        __syncthreads();
        {
            int r = t >> 8, f = t & 255, row = p * 4 + r;
            float s = 0.f;
            #pragma unroll
            for (int uu = 0; uu < 8; ++uu) s += part[uu * 1024 + r * 256 + f];
            ph2[f * 8 + row] = s;
        }
        __syncthreads();
    }
    if (t < 256) {   // final: +b2, relu, masked pool (f = t)
        float bb = b2[t];
        float hp = 0.f, sp = 0.f;
        #pragma unroll
        for (int r = 0; r < 8; ++r) {
            float p = fmaxf(ph2[t * 8 + r] + bb, 0.f);
            sp += p;
            hp = fmaf(p, hmv[r], hp);
        }
        atomicAdd(&hsum[b * 256 + t], hp);
        atomicAdd(&asum[b * 256 + t], sp - hp);
    }
}

// ---------------------------------------------------------------------------
// k_rho: out[b] = 0.5 + 0.5*tanh(rho(home)-rho(away)); b2 cancels.
// ---------------------------------------------------------------------------
__global__ __launch_bounds__(256) void k_rho(const float* __restrict__ hsum,
        const float* __restrict__ asum,
        const float* __restrict__ w1, const float* __restrict__ b1,
        const float* __restrict__ w2, const float* __restrict__ b2,
        float* __restrict__ out) {
    const int bIdx = blockIdx.x;
    const int t = threadIdx.x, q = t & 31, u = t >> 5;
    __shared__ __align__(16) float part[2048];
    __shared__ __align__(16) float sv[512];
    __shared__ float wsv[2];
    sv[t] = hsum[bIdx * 256 + t];
    sv[256 + t] = asum[bIdx * 256 + t];
    __syncthreads();
    float aH[4] = {0.f, 0.f, 0.f, 0.f}, aA[4] = {0.f, 0.f, 0.f, 0.f};
    #pragma unroll 8
    for (int kk = 0; kk < 32; ++kk) {
        int k = u * 32 + kk;
        float4 w4 = *(const float4*)&w1[(size_t)k * 128 + q * 4];
        float sh = sv[k], sa = sv[256 + k];
        aH[0] = fmaf(sh, w4.x, aH[0]); aA[0] = fmaf(sa, w4.x, aA[0]);
        aH[1] = fmaf(sh, w4.y, aH[1]); aA[1] = fmaf(sa, w4.y, aA[1]);
        aH[2] = fmaf(sh, w4.z, aH[2]); aA[2] = fmaf(sa, w4.z, aA[2]);
        aH[3] = fmaf(sh, w4.w, aH[3]); aA[3] = fmaf(sa, w4.w, aA[3]);
    }
    *(float4*)&part[u * 256 + q * 4]       = make_float4(aH[0], aH[1], aH[2], aH[3]);
    *(float4*)&part[u * 256 + 128 + q * 4] = make_float4(aA[0], aA[1], aA[2], aA[3]);
    __syncthreads();
    if (t < 64) {
        int vec = t >> 5, fq = t & 31;
        float4 s = make_float4(0.f, 0.f, 0.f, 0.f);
        #pragma unroll
        for (int uu = 0; uu < 8; ++uu) {
            float4 p = *(const float4*)&part[uu * 256 + vec * 128 + fq * 4];
            s.x += p.x; s.y += p.y; s.z += p.z; s.w += p.w;
        }
        float4 bb = *(const float4*)&b1[fq * 4];
        float4 w2q = *(const float4*)&w2[fq * 4];
        float p = fmaxf(s.x + bb.x, 0.f) * w2q.x
                + fmaxf(s.y + bb.y, 0.f) * w2q.y
                + fmaxf(s.z + bb.z, 0.f) * w2q.z
                + fmaxf(s.w + bb.w, 0.f) * w2q.w;
        #pragma unroll
        for (int o = 16; o > 0; o >>= 1) p += __shfl_down(p, o, 32);
        if ((t & 31) == 0) wsv[vec] = p;
    }
    __syncthreads();
    if (t == 0) out[bIdx] = 0.5f + 0.5f * tanhf(wsv[0] - wsv[1]);
}

// ---------------------------------------------------------------------------
extern "C" void kernel_launch(void* const* d_in, const int* in_sizes, int n_in,
                              void* d_out, int out_size, void* d_ws, size_t ws_size,
                              hipStream_t stream) {
    const float* A         = (const float*)d_in[0];
    const float* X         = (const float*)d_in[1];
    const float* home_mask = (const float*)d_in[2];
    const float* emb1_w    = (const float*)d_in[3];
    const float* emb1_b    = (const float*)d_in[4];
    const float* emb2_w    = (const float*)d_in[5];
    const float* emb2_b    = (const float*)d_in[6];
    const float* rgcn_w[2]    = { (const float*)d_in[7],  (const float*)d_in[14] };
    const float* rgcn_root[2] = { (const float*)d_in[8],  (const float*)d_in[15] };
    const float* rgcn_bias[2] = { (const float*)d_in[9],  (const float*)d_in[16] };
    const float* lina_w[2]    = { (const float*)d_in[10], (const float*)d_in[17] };
    const float* lina_b[2]    = { (const float*)d_in[11], (const float*)d_in[18] };
    const float* linb_w[2]    = { (const float*)d_in[12], (const float*)d_in[19] };
    const float* linb_b[2]    = { (const float*)d_in[13], (const float*)d_in[20] };
    const float* norm_g  = (const float*)d_in[21];
    const float* norm_b  = (const float*)d_in[22];
    const float* phi_w1  = (const float*)d_in[23];
    const float* phi_b1  = (const float*)d_in[24];
    const float* phi_w2  = (const float*)d_in[25];
    const float* phi_b2  = (const float*)d_in[26];
    const float* rho_w1  = (const float*)d_in[27];
    const float* rho_b1  = (const float*)d_in[28];
    const float* rho_w2  = (const float*)d_in[29];
    const float* rho_b2  = (const float*)d_in[30];
    float* out = (float*)d_out;

    float* ws   = (float*)d_ws;
    float* H    = ws;               // 262144
    float* H2   = ws + 262144;      // 262144
    float* hsum = ws + 524288;      // 2048
    float* asum = ws + 526336;      // 2048 (contiguous with hsum)

    k_embed<<<256, 1024, 0, stream>>>(X, emb1_w, emb1_b, emb2_w, emb2_b, H, hsum);

    for (int it = 0; it < 2; ++it) {
        k_gcn1<<<256, 1024, 0, stream>>>(A, H, rgcn_w[it], rgcn_root[it],
                                         rgcn_bias[it], H2);
        k_gcn2<<<256, 1024, 0, stream>>>(A, H2, norm_g, norm_b,
                                         lina_w[it], lina_b[it],
                                         linb_w[it], linb_b[it], H);
    }

    k_deepset<<<256, 1024, 0, stream>>>(H, home_mask, phi_w1, phi_b1,
                                        phi_w2, phi_b2, hsum, asum);
    k_rho<<<NB, 256, 0, stream>>>(hsum, asum, rho_w1, rho_b1, rho_w2, rho_b2, out);
}